// Round 3
// baseline (388.860 us; speedup 1.0000x reference)
//
#include <hip/hip_runtime.h>

typedef __attribute__((ext_vector_type(8))) short bfrag8;   // 8 x bf16 (4 VGPRs)
typedef __attribute__((ext_vector_type(4))) float f32x4;    // MFMA accumulator

typedef const unsigned int __attribute__((address_space(1)))* gas1_u32;
typedef unsigned int __attribute__((address_space(3)))* gas3_u32;

#define DEV __device__ __forceinline__

DEV unsigned short f2bf(float f) {              // f32 -> bf16 bits, RNE
  unsigned int u = __builtin_bit_cast(unsigned int, f);
  u += 0x7fffu + ((u >> 16) & 1u);
  return (unsigned short)(u >> 16);
}

DEV void gload_lds16(const void* g, void* l) {  // async global->LDS, 16B/lane
  __builtin_amdgcn_global_load_lds((gas1_u32)g, (gas3_u32)l, 16, 0, 0);
}

// ---------------- per-row stats of x + raw bf16 cast (one wave per row) ---------------
__global__ __launch_bounds__(256) void k_xstats(
    const float* __restrict__ x, unsigned short* __restrict__ xb,
    float* __restrict__ mu, float* __restrict__ rstd)
{
  const int wid = threadIdx.x >> 6, lane = threadIdx.x & 63;
  const int row = blockIdx.x * 4 + wid;
  const float* base = x + (size_t)row * 1024;
  float4 v[4];
  #pragma unroll
  for (int i = 0; i < 4; ++i) v[i] = ((const float4*)base)[i * 64 + lane];
  float s = 0.f, q = 0.f;
  #pragma unroll
  for (int i = 0; i < 4; ++i) {
    s += v[i].x + v[i].y + v[i].z + v[i].w;
    q += v[i].x*v[i].x + v[i].y*v[i].y + v[i].z*v[i].z + v[i].w*v[i].w;
  }
  #pragma unroll
  for (int off = 32; off >= 1; off >>= 1) { s += __shfl_xor(s, off); q += __shfl_xor(q, off); }
  const float m  = s * (1.0f/1024.0f);
  const float var = q * (1.0f/1024.0f) - m * m;
  const float rs = rsqrtf(var + 1e-5f);
  if (lane == 0) { mu[row] = m; rstd[row] = rs; }
  unsigned short* ob = xb + (size_t)row * 1024;
  #pragma unroll
  for (int i = 0; i < 4; ++i) {
    ushort4 o;
    o.x = f2bf(v[i].x); o.y = f2bf(v[i].y); o.z = f2bf(v[i].z); o.w = f2bf(v[i].w);
    ((ushort4*)ob)[i * 64 + lane] = o;
  }
}

// ---------------- full LN of latents -> bf16 (block per row of 2048) ---------------
__global__ __launch_bounds__(256) void k_lnlat(
    const float* __restrict__ lat, const float* __restrict__ w,
    const float* __restrict__ b, unsigned short* __restrict__ ln)
{
  const int row = blockIdx.x, tid = threadIdx.x;
  const float* base = lat + (size_t)row * 2048;
  const float4 v0 = ((const float4*)base)[tid];
  const float4 v1 = ((const float4*)base)[256 + tid];
  float s = v0.x+v0.y+v0.z+v0.w + v1.x+v1.y+v1.z+v1.w;
  float q = v0.x*v0.x+v0.y*v0.y+v0.z*v0.z+v0.w*v0.w
          + v1.x*v1.x+v1.y*v1.y+v1.z*v1.z+v1.w*v1.w;
  #pragma unroll
  for (int off = 32; off >= 1; off >>= 1) { s += __shfl_xor(s, off); q += __shfl_xor(q, off); }
  __shared__ float red[8];
  const int wid = tid >> 6, lane = tid & 63;
  if (lane == 0) { red[wid] = s; red[4 + wid] = q; }
  __syncthreads();
  s = red[0] + red[1] + red[2] + red[3];
  q = red[4] + red[5] + red[6] + red[7];
  const float m  = s * (1.0f/2048.0f);
  const float var = q * (1.0f/2048.0f) - m * m;
  const float rs = rsqrtf(var + 1e-5f);
  const float4 w0 = ((const float4*)w)[tid], w1 = ((const float4*)w)[256 + tid];
  const float4 b0 = ((const float4*)b)[tid], b1 = ((const float4*)b)[256 + tid];
  ushort4 o0, o1;
  o0.x = f2bf((v0.x - m) * rs * w0.x + b0.x);
  o0.y = f2bf((v0.y - m) * rs * w0.y + b0.y);
  o0.z = f2bf((v0.z - m) * rs * w0.z + b0.z);
  o0.w = f2bf((v0.w - m) * rs * w0.w + b0.w);
  o1.x = f2bf((v1.x - m) * rs * w1.x + b1.x);
  o1.y = f2bf((v1.y - m) * rs * w1.y + b1.y);
  o1.z = f2bf((v1.z - m) * rs * w1.z + b1.z);
  o1.w = f2bf((v1.w - m) * rs * w1.w + b1.w);
  ((ushort4*)(ln + (size_t)row * 2048))[tid] = o0;
  ((ushort4*)(ln + (size_t)row * 2048))[256 + tid] = o1;
}

// ---------------- tiled transpose + bf16 cast: src[K][N] f32 -> dst[N][K] bf16 --------
__global__ __launch_bounds__(256) void k_transpose_cast(
    const float* __restrict__ src, unsigned short* __restrict__ dst,
    int K, int N, const float* __restrict__ rowscale, float scale)
{
  __shared__ float tile[32][33];
  const int tx = threadIdx.x & 31, ty = threadIdx.x >> 5;
  const int ntiles = N >> 5;
  const int k0 = (blockIdx.x / ntiles) << 5;
  const int n0 = (blockIdx.x % ntiles) << 5;
  #pragma unroll
  for (int r = 0; r < 4; ++r) {
    const int kk = ty + r * 8;
    float v = src[(size_t)(k0 + kk) * N + n0 + tx] * scale;
    if (rowscale) v *= rowscale[k0 + kk];
    tile[kk][tx] = v;
  }
  __syncthreads();
  #pragma unroll
  for (int r = 0; r < 4; ++r) {
    const int nn = ty + r * 8;
    dst[(size_t)(n0 + nn) * K + k0 + tx] = f2bf(tile[tx][nn]);
  }
}

// ---------------- c1/c2 two-stage deterministic reduce -------------------------------
__global__ __launch_bounds__(256) void k_c1c2_part(
    const float* __restrict__ Wkv, const float* __restrict__ w,
    const float* __restrict__ b, float* __restrict__ part)
{
  const int kc = blockIdx.x;                 // 16 chunks of 64 k-rows
  const int n  = blockIdx.y * 256 + threadIdx.x;
  float s1 = 0.f, s2 = 0.f;
  const int k0 = kc * 64;
  for (int k = k0; k < k0 + 64; ++k) {
    const float wv = Wkv[(size_t)k * 1024 + n];
    s1 += w[k] * wv;
    s2 += b[k] * wv;
  }
  part[(size_t)(kc * 2 + 0) * 1024 + n] = s1;
  part[(size_t)(kc * 2 + 1) * 1024 + n] = s2;
}

__global__ __launch_bounds__(256) void k_c1c2_red(
    const float* __restrict__ part, float* __restrict__ c1, float* __restrict__ c2)
{
  const int n = blockIdx.x * 256 + threadIdx.x;
  float s1 = 0.f, s2 = 0.f;
  #pragma unroll
  for (int kc = 0; kc < 16; ++kc) {
    s1 += part[(size_t)(kc * 2 + 0) * 1024 + n];
    s2 += part[(size_t)(kc * 2 + 1) * 1024 + n];
  }
  c1[n] = s1; c2[n] = s2;
}

// ---------------- pipelined GEMM: C = A (M x K bf16) @ Bt^T ([N][K] bf16) -------------
// 4 LDS regions (BK=32), depth-3 prefetch, counted vmcnt(8) + raw asm barrier per step.
// Hazards: (a) reads of region t gated by [each wave: vmcnt(8) forces own stage(t)
// landed] + barrier; (b) stage(t+3) writes region read at t-1, whose ds_reads finished
// before each wave reached barrier(t); (c) tail uses wrap-around dummy stages to keep
// vmcnt accounting uniform (they write dead regions only).
// Rotation swizzle: LDS row r holds its four 16B k-slots rotated by (r>>1)&3 so the 8
// consecutive lanes of a b128 read hit 8 distinct 16B slots (conflict-free).
// MODE 0: kv epilogue  kv = rstd*(acc - mu*c1) + c2  -> bf16
// MODE 1: plain -> bf16        MODE 2: plain -> f32
template<int BM, int BN, int WM, int WN, int NT, int MODE>
__global__ __launch_bounds__(NT, 2) void k_gemm(
    const unsigned short* __restrict__ A, int lda,
    const unsigned short* __restrict__ Bt, int ldb,
    int K, int mtiles, int ntiles,
    void* __restrict__ Cout, int ldc,
    const float* __restrict__ mu, const float* __restrict__ rstd,
    const float* __restrict__ c1, const float* __restrict__ c2)
{
  constexpr int BK = 32;
  constexpr int NW = NT / 64;
  constexpr int MF = (BM / WM) / 16;
  constexpr int NF = (BN / WN) / 16;
  constexpr int LA = (BM * BK) / (8 * NT);   // 16B loads per thread for A region
  constexpr int LB = (BN * BK) / (8 * NT);
  constexpr int RA = BM * BK;                // region sizes in elements
  constexpr int RB = BN * BK;
  static_assert(WM * WN == NW, "wave grid");
  static_assert(LA >= 1 && LB >= 1, "tile too small for NT");

  __shared__ __attribute__((aligned(16))) unsigned short As[4 * RA];
  __shared__ __attribute__((aligned(16))) unsigned short Bs[4 * RB];

  // bijective chunked XCD swizzle (all launches have nwg % 8 == 0)
  int bid = blockIdx.x;
  {
    const int nwg = gridDim.x;
    if ((nwg & 7) == 0) {
      const int q = nwg >> 3;
      bid = (bid & 7) * q + (bid >> 3);
    }
  }
  const int mt = bid / ntiles, nt = bid % ntiles;  // nt fastest: neighbors share A panel
  const int tid = threadIdx.x;
  const int wid = tid >> 6, lane = tid & 63;
  const int g = lane >> 4, c = lane & 15;
  const int wr = wid / WN, wc = wid % WN;
  const int MO = wr * (BM / WM), NO = wc * (BN / WN);
  const int rot = (c >> 1) & 3;                    // read-side slot rotation

  const unsigned short* gA = A + (size_t)mt * BM * lda;
  const unsigned short* gB = Bt + (size_t)nt * BN * ldb;

  const f32x4 zz = {0.f, 0.f, 0.f, 0.f};
  f32x4 acc[MF][NF];
  #pragma unroll
  for (int m = 0; m < MF; ++m)
    #pragma unroll
    for (int n = 0; n < NF; ++n) acc[m][n] = zz;

  // stage region R with K-step kt: LDS dest linear; global source slot-rotated
  auto stage = [&](int R, int kt) {
    #pragma unroll
    for (int i = 0; i < LA; ++i) {
      const int o = (i * NT + tid) * 16;           // linear LDS byte offset in region
      const int row = o >> 6;
      const int slot = (o >> 4) & 3;
      const int srcb = (((slot - ((row >> 1) & 3)) & 3) << 4);
      gload_lds16((const char*)(gA + (size_t)row * lda + kt * BK) + srcb,
                  (char*)(As + R * RA) + o);
    }
    #pragma unroll
    for (int i = 0; i < LB; ++i) {
      const int o = (i * NT + tid) * 16;
      const int row = o >> 6;
      const int slot = (o >> 4) & 3;
      const int srcb = (((slot - ((row >> 1) & 3)) & 3) << 4);
      gload_lds16((const char*)(gB + (size_t)row * ldb + kt * BK) + srcb,
                  (char*)(Bs + R * RB) + o);
    }
  };

  auto compute = [&](int R) {
    const char* as = (const char*)(As + R * RA);
    const char* bs = (const char*)(Bs + R * RB);
    bfrag8 af[MF], bf[NF];
    #pragma unroll
    for (int m = 0; m < MF; ++m) {
      const int rw = MO + m * 16 + c;
      af[m] = *(const bfrag8*)(as + rw * 64 + (((g + rot) & 3) << 4));
    }
    #pragma unroll
    for (int n = 0; n < NF; ++n) {
      const int rw = NO + n * 16 + c;
      bf[n] = *(const bfrag8*)(bs + rw * 64 + (((g + rot) & 3) << 4));
    }
    #pragma unroll
    for (int m = 0; m < MF; ++m)
      #pragma unroll
      for (int n = 0; n < NF; ++n)
        acc[m][n] = __builtin_amdgcn_mfma_f32_16x16x32_bf16(af[m], bf[n], acc[m][n], 0, 0, 0);
  };

  const int nkt = K / BK;                    // 32 / 64 / 16 here; all % 4 == 0
  stage(0, 0); stage(1, 1); stage(2, 2);
  for (int t = 0; t < nkt; t += 4) {
    #pragma unroll
    for (int r = 0; r < 4; ++r) {
      int t3 = t + r + 3; if (t3 >= nkt) t3 -= nkt;   // tail: dummy wrap stages
      asm volatile("s_waitcnt vmcnt(8)\n\ts_barrier" ::: "memory");
      stage((r + 3) & 3, t3);
      compute(r);
    }
  }

  #pragma unroll
  for (int m = 0; m < MF; ++m) {
    #pragma unroll
    for (int j = 0; j < 4; ++j) {
      const size_t orow = (size_t)mt * BM + MO + m * 16 + g * 4 + j;
      float rs = 0.f, muv = 0.f;
      if constexpr (MODE == 0) { rs = rstd[orow]; muv = mu[orow]; }
      #pragma unroll
      for (int n = 0; n < NF; ++n) {
        const int gcol = nt * BN + NO + n * 16 + c;
        float v = acc[m][n][j];
        if constexpr (MODE == 0) v = rs * (v - muv * c1[gcol]) + c2[gcol];
        if constexpr (MODE == 2) ((float*)Cout)[orow * ldc + gcol] = v;
        else ((unsigned short*)Cout)[orow * ldc + gcol] = f2bf(v);
      }
    }
  }
}

// ---------------- flash attention per (bt, head): 4 waves x 16 queries ----------------
__global__ __launch_bounds__(256) void k_attn(
    const unsigned short* __restrict__ q,   // [BT*64][512] bf16 (scale 1/8 pre-folded)
    const unsigned short* __restrict__ kv,  // [BT*1024][1024] bf16: k | v
    unsigned short* __restrict__ ao)        // [BT*64][512] bf16
{
  __shared__ __attribute__((aligned(16))) unsigned short Vt[64 * 64];  // [d][key] swizzled
  const int bid = blockIdx.x;
  const int bt = bid >> 3, h = bid & 7;
  const int tid = threadIdx.x;
  const int wid = tid >> 6, lane = tid & 63;
  const int g = lane >> 4, c = lane & 15;

  const size_t qoff = ((size_t)bt * 64 + wid * 16 + c) * 512 + h * 64;
  const bfrag8 qf0 = *(const bfrag8*)(q + qoff + g * 8);
  const bfrag8 qf1 = *(const bfrag8*)(q + qoff + 32 + g * 8);

  const f32x4 zz = {0.f, 0.f, 0.f, 0.f};
  f32x4 o[4] = {zz, zz, zz, zz};
  float m_run = -1e30f, l_run = 0.f;

  const size_t kvbase = (size_t)bt * 1024 * 1024;
  const unsigned short* kbase = kv + kvbase + h * 64;
  const unsigned short* vbase = kv + kvbase + 512 + h * 64;

  for (int ch = 0; ch < 16; ++ch) {            // 16 chunks of 64 keys
    #pragma unroll
    for (int rr = 0; rr < 2; ++rr) {           // stage V transposed + XOR-swizzled
      const int key = rr * 32 + (tid >> 3);
      const int d0 = (tid & 7) * 8;
      const bfrag8 vv = *(const bfrag8*)(vbase + (size_t)(ch * 64 + key) * 1024 + d0);
      #pragma unroll
      for (int j = 0; j < 8; ++j)
        Vt[(d0 + j) * 64 + (key ^ (j << 3))] = (unsigned short)vv[j];
    }
    __syncthreads();
    #pragma unroll
    for (int ks = 0; ks < 2; ++ks) {           // 2 x 32-key steps
      const int kb = ch * 64 + ks * 32;
      f32x4 s[2];
      #pragma unroll
      for (int t = 0; t < 2; ++t) {            // key permutation: row m -> key 8*(m>>2)+4t+(m&3)
        const int kr = ((c >> 2) << 3) + (t << 2) + (c & 3);
        const unsigned short* krow = kbase + (size_t)(kb + kr) * 1024;
        s[t] = zz;
        s[t] = __builtin_amdgcn_mfma_f32_16x16x32_bf16(*(const bfrag8*)(krow + g * 8),      qf0, s[t], 0, 0, 0);
        s[t] = __builtin_amdgcn_mfma_f32_16x16x32_bf16(*(const bfrag8*)(krow + 32 + g * 8), qf1, s[t], 0, 0, 0);
      }
      float pm = s[0][0];
      #pragma unroll
      for (int i = 1; i < 4; ++i) pm = fmaxf(pm, s[0][i]);
      #pragma unroll
      for (int i = 0; i < 4; ++i) pm = fmaxf(pm, s[1][i]);
      pm = fmaxf(pm, __shfl_xor(pm, 16));
      pm = fmaxf(pm, __shfl_xor(pm, 32));
      const float mn = fmaxf(m_run, pm);
      const float alpha = __expf(m_run - mn);
      float p[8];
      #pragma unroll
      for (int i = 0; i < 4; ++i) p[i]     = __expf(s[0][i] - mn);
      #pragma unroll
      for (int i = 0; i < 4; ++i) p[4 + i] = __expf(s[1][i] - mn);
      float ts = 0.f;
      #pragma unroll
      for (int i = 0; i < 8; ++i) ts += p[i];
      ts += __shfl_xor(ts, 16);
      ts += __shfl_xor(ts, 32);
      l_run = l_run * alpha + ts;
      m_run = mn;
      float ar[4];
      #pragma unroll
      for (int rj = 0; rj < 4; ++rj) ar[rj] = __shfl(alpha, g * 4 + rj);
      #pragma unroll
      for (int db = 0; db < 4; ++db)
        #pragma unroll
        for (int j = 0; j < 4; ++j) o[db][j] *= ar[j];
      bfrag8 pa;
      #pragma unroll
      for (int i = 0; i < 8; ++i) pa[i] = (short)f2bf(p[i]);
      #pragma unroll
      for (int db = 0; db < 4; ++db) {
        const int d = db * 16 + c;
        const bfrag8 vb = *(const bfrag8*)(Vt + d * 64 + ((ks * 32 + g * 8) ^ ((c & 7) << 3)));
        o[db] = __builtin_amdgcn_mfma_f32_16x16x32_bf16(pa, vb, o[db], 0, 0, 0);
      }
    }
    __syncthreads();
  }
  float lr[4];
  #pragma unroll
  for (int rj = 0; rj < 4; ++rj) lr[rj] = __shfl(l_run, g * 4 + rj);
  #pragma unroll
  for (int db = 0; db < 4; ++db)
    #pragma unroll
    for (int j = 0; j < 4; ++j) {
      const float val = o[db][j] / lr[j];
      ao[((size_t)bt * 64 + wid * 16 + g * 4 + j) * 512 + h * 64 + db * 16 + c] = f2bf(val);
    }
}

// --------------------------------- launch -------------------------------------------
extern "C" void kernel_launch(void* const* d_in, const int* in_sizes, int n_in,
                              void* d_out, int out_size, void* d_ws, size_t ws_size,
                              hipStream_t stream)
{
  const float* x    = (const float*)d_in[0];
  const float* lat  = (const float*)d_in[1];
  const float* nm_w = (const float*)d_in[2];
  const float* nm_b = (const float*)d_in[3];
  const float* nl_w = (const float*)d_in[4];
  const float* nl_b = (const float*)d_in[5];
  const float* Wq   = (const float*)d_in[6];
  const float* Wkv  = (const float*)d_in[7];
  const float* Wout = (const float*)d_in[8];

  char* p = (char*)d_ws;
  auto take = [&](size_t bytes) { char* r = p; p += (bytes + 255) & ~(size_t)255; return r; };
  unsigned short* xb    = (unsigned short*)take(64ull * 1024 * 1024 * 2);  // bf16(x)
  unsigned short* kvb   = (unsigned short*)take(64ull * 1024 * 1024 * 2);  // kv bf16
  unsigned short* lnb   = (unsigned short*)take(4096ull * 2048 * 2);       // LN(latents)
  unsigned short* qbuf  = (unsigned short*)take(4096ull * 512 * 2);        // q (scaled)
  unsigned short* aob   = (unsigned short*)take(4096ull * 512 * 2);        // attn out
  unsigned short* WqT   = (unsigned short*)take(512ull * 2048 * 2);
  unsigned short* WkvT  = (unsigned short*)take(1024ull * 1024 * 2);
  unsigned short* WoutT = (unsigned short*)take(2048ull * 512 * 2);
  float* muv  = (float*)take(65536ull * 4);
  float* rsd  = (float*)take(65536ull * 4);
  float* c1   = (float*)take(1024 * 4);
  float* c2   = (float*)take(1024 * 4);
  float* part = (float*)take(32ull * 1024 * 4);
  if ((size_t)(p - (char*)d_ws) > ws_size) return;  // insufficient workspace: fail loudly

  k_transpose_cast<<<dim3(64 * 16), 256, 0, stream>>>(Wq,   WqT,   2048,  512, nullptr, 0.125f);
  k_transpose_cast<<<dim3(32 * 32), 256, 0, stream>>>(Wkv,  WkvT,  1024, 1024, nm_w,    1.0f);
  k_transpose_cast<<<dim3(16 * 64), 256, 0, stream>>>(Wout, WoutT,  512, 2048, nullptr, 1.0f);
  k_c1c2_part<<<dim3(16, 4), 256, 0, stream>>>(Wkv, nm_w, nm_b, part);
  k_c1c2_red<<<dim3(4), 256, 0, stream>>>(part, c1, c2);
  k_xstats<<<dim3(16384), 256, 0, stream>>>(x, xb, muv, rsd);
  k_lnlat<<<dim3(4096), 256, 0, stream>>>(lat, nl_w, nl_b, lnb);

  // kv = LN(x) @ Wkv (LN in epilogue): single GEMM [65536 x 1024 x K=1024]
  k_gemm<256, 256, 2, 4, 512, 0><<<dim3(1024), 512, 0, stream>>>(
      xb, 1024, WkvT, 1024, 1024, 256, 4, kvb, 1024, muv, rsd, c1, c2);
  // q = LN(latents) @ (Wq/8): single GEMM [4096 x 512 x K=2048]
  k_gemm<128, 128, 2, 2, 256, 1><<<dim3(128), 256, 0, stream>>>(
      lnb, 2048, WqT, 2048, 2048, 32, 4, qbuf, 512, nullptr, nullptr, nullptr, nullptr);

  k_attn<<<dim3(512), 256, 0, stream>>>(qbuf, kvb, aob);

  // out = attnout @ Wout: single GEMM [4096 x 2048 x K=512] -> f32
  k_gemm<128, 128, 2, 2, 256, 2><<<dim3(512), 256, 0, stream>>>(
      aob, 512, WoutT, 512, 512, 32, 16, d_out, 2048, nullptr, nullptr, nullptr, nullptr);
}

// Round 5
// 378.353 us; speedup vs baseline: 1.0278x; 1.0278x over previous
//
#include <hip/hip_runtime.h>

typedef __attribute__((ext_vector_type(8))) short bfrag8;   // 8 x bf16 (4 VGPRs)
typedef __attribute__((ext_vector_type(4))) float f32x4;    // MFMA accumulator

typedef const unsigned int __attribute__((address_space(1)))* gas1_u32;
typedef unsigned int __attribute__((address_space(3)))* gas3_u32;

#define DEV __device__ __forceinline__

DEV unsigned short f2bf(float f) {              // f32 -> bf16 bits, RNE
  unsigned int u = __builtin_bit_cast(unsigned int, f);
  u += 0x7fffu + ((u >> 16) & 1u);
  return (unsigned short)(u >> 16);
}

DEV void gload_lds16(const void* g, void* l) {  // async global->LDS, 16B/lane
  __builtin_amdgcn_global_load_lds((gas1_u32)g, (gas3_u32)l, 16, 0, 0);
}

// counted-wait + barrier; N must cover exactly the stages that may stay in flight
template<int N> DEV void gate_bar();
template<> DEV void gate_bar<4>() { asm volatile("s_waitcnt vmcnt(4)\n\ts_barrier" ::: "memory"); }
template<> DEV void gate_bar<6>() { asm volatile("s_waitcnt vmcnt(6)\n\ts_barrier" ::: "memory"); }
template<> DEV void gate_bar<8>() { asm volatile("s_waitcnt vmcnt(8)\n\ts_barrier" ::: "memory"); }

// ---------------- per-row stats of x + raw bf16 cast (one wave per row) ---------------
__global__ __launch_bounds__(256) void k_xstats(
    const float* __restrict__ x, unsigned short* __restrict__ xb,
    float* __restrict__ mu, float* __restrict__ rstd)
{
  const int wid = threadIdx.x >> 6, lane = threadIdx.x & 63;
  const int row = blockIdx.x * 4 + wid;
  const float* base = x + (size_t)row * 1024;
  float4 v[4];
  #pragma unroll
  for (int i = 0; i < 4; ++i) v[i] = ((const float4*)base)[i * 64 + lane];
  float s = 0.f, q = 0.f;
  #pragma unroll
  for (int i = 0; i < 4; ++i) {
    s += v[i].x + v[i].y + v[i].z + v[i].w;
    q += v[i].x*v[i].x + v[i].y*v[i].y + v[i].z*v[i].z + v[i].w*v[i].w;
  }
  #pragma unroll
  for (int off = 32; off >= 1; off >>= 1) { s += __shfl_xor(s, off); q += __shfl_xor(q, off); }
  const float m  = s * (1.0f/1024.0f);
  const float var = q * (1.0f/1024.0f) - m * m;
  const float rs = rsqrtf(var + 1e-5f);
  if (lane == 0) { mu[row] = m; rstd[row] = rs; }
  unsigned short* ob = xb + (size_t)row * 1024;
  #pragma unroll
  for (int i = 0; i < 4; ++i) {
    ushort4 o;
    o.x = f2bf(v[i].x); o.y = f2bf(v[i].y); o.z = f2bf(v[i].z); o.w = f2bf(v[i].w);
    ((ushort4*)ob)[i * 64 + lane] = o;
  }
}

// ---------------- full LN of latents -> bf16 (block per row of 2048) ---------------
__global__ __launch_bounds__(256) void k_lnlat(
    const float* __restrict__ lat, const float* __restrict__ w,
    const float* __restrict__ b, unsigned short* __restrict__ ln)
{
  const int row = blockIdx.x, tid = threadIdx.x;
  const float* base = lat + (size_t)row * 2048;
  const float4 v0 = ((const float4*)base)[tid];
  const float4 v1 = ((const float4*)base)[256 + tid];
  float s = v0.x+v0.y+v0.z+v0.w + v1.x+v1.y+v1.z+v1.w;
  float q = v0.x*v0.x+v0.y*v0.y+v0.z*v0.z+v0.w*v0.w
          + v1.x*v1.x+v1.y*v1.y+v1.z*v1.z+v1.w*v1.w;
  #pragma unroll
  for (int off = 32; off >= 1; off >>= 1) { s += __shfl_xor(s, off); q += __shfl_xor(q, off); }
  __shared__ float red[8];
  const int wid = tid >> 6, lane = tid & 63;
  if (lane == 0) { red[wid] = s; red[4 + wid] = q; }
  __syncthreads();
  s = red[0] + red[1] + red[2] + red[3];
  q = red[4] + red[5] + red[6] + red[7];
  const float m  = s * (1.0f/2048.0f);
  const float var = q * (1.0f/2048.0f) - m * m;
  const float rs = rsqrtf(var + 1e-5f);
  const float4 w0 = ((const float4*)w)[tid], w1 = ((const float4*)w)[256 + tid];
  const float4 b0 = ((const float4*)b)[tid], b1 = ((const float4*)b)[256 + tid];
  ushort4 o0, o1;
  o0.x = f2bf((v0.x - m) * rs * w0.x + b0.x);
  o0.y = f2bf((v0.y - m) * rs * w0.y + b0.y);
  o0.z = f2bf((v0.z - m) * rs * w0.z + b0.z);
  o0.w = f2bf((v0.w - m) * rs * w0.w + b0.w);
  o1.x = f2bf((v1.x - m) * rs * w1.x + b1.x);
  o1.y = f2bf((v1.y - m) * rs * w1.y + b1.y);
  o1.z = f2bf((v1.z - m) * rs * w1.z + b1.z);
  o1.w = f2bf((v1.w - m) * rs * w1.w + b1.w);
  ((ushort4*)(ln + (size_t)row * 2048))[tid] = o0;
  ((ushort4*)(ln + (size_t)row * 2048))[256 + tid] = o1;
}

// ---------------- tiled transpose + bf16 cast: src[K][N] f32 -> dst[N][K] bf16 --------
__global__ __launch_bounds__(256) void k_transpose_cast(
    const float* __restrict__ src, unsigned short* __restrict__ dst,
    int K, int N, const float* __restrict__ rowscale, float scale)
{
  __shared__ float tile[32][33];
  const int tx = threadIdx.x & 31, ty = threadIdx.x >> 5;
  const int ntiles = N >> 5;
  const int k0 = (blockIdx.x / ntiles) << 5;
  const int n0 = (blockIdx.x % ntiles) << 5;
  #pragma unroll
  for (int r = 0; r < 4; ++r) {
    const int kk = ty + r * 8;
    float v = src[(size_t)(k0 + kk) * N + n0 + tx] * scale;
    if (rowscale) v *= rowscale[k0 + kk];
    tile[kk][tx] = v;
  }
  __syncthreads();
  #pragma unroll
  for (int r = 0; r < 4; ++r) {
    const int nn = ty + r * 8;
    dst[(size_t)(n0 + nn) * K + k0 + tx] = f2bf(tile[tx][nn]);
  }
}

// ---------------- c1/c2 two-stage deterministic reduce -------------------------------
__global__ __launch_bounds__(256) void k_c1c2_part(
    const float* __restrict__ Wkv, const float* __restrict__ w,
    const float* __restrict__ b, float* __restrict__ part)
{
  const int kc = blockIdx.x;                 // 16 chunks of 64 k-rows
  const int n  = blockIdx.y * 256 + threadIdx.x;
  float s1 = 0.f, s2 = 0.f;
  const int k0 = kc * 64;
  for (int k = k0; k < k0 + 64; ++k) {
    const float wv = Wkv[(size_t)k * 1024 + n];
    s1 += w[k] * wv;
    s2 += b[k] * wv;
  }
  part[(size_t)(kc * 2 + 0) * 1024 + n] = s1;
  part[(size_t)(kc * 2 + 1) * 1024 + n] = s2;
}

__global__ __launch_bounds__(256) void k_c1c2_red(
    const float* __restrict__ part, float* __restrict__ c1, float* __restrict__ c2)
{
  const int n = blockIdx.x * 256 + threadIdx.x;
  float s1 = 0.f, s2 = 0.f;
  #pragma unroll
  for (int kc = 0; kc < 16; ++kc) {
    s1 += part[(size_t)(kc * 2 + 0) * 1024 + n];
    s2 += part[(size_t)(kc * 2 + 1) * 1024 + n];
  }
  c1[n] = s1; c2[n] = s2;
}

// =====================================================================================
// kv GEMM, 8-phase schedule. C[65536x1024] = A[65536x1024] @ Bt^T ([1024][1024]),
// LN folded in epilogue. Tile 256x256, BK=64 (2 kk-halves of 32), 8 waves (2Mx4N).
// LDS: A[2buf][2kk][256][32] (64KB) + B same (64KB). Phase = {ds_reads, 1 half-tile
// stage, barrier, lgkmcnt(0), setprio, 16 MFMA, setprio(0), [vmcnt(4)], barrier}.
// Steady-state queue walk (2 loads/half-tile): at every read-gate the oldest 4
// outstanding loads are exactly the halves the next phase reads; vmcnt(4) lands
// them while keeping 2 halves in flight.
// =====================================================================================
#define BAR8   __builtin_amdgcn_s_barrier()
#define GATE4  do { gate_bar<4>(); __builtin_amdgcn_sched_barrier(0); } while (0)
#define LGKM0  do { asm volatile("s_waitcnt lgkmcnt(0)" ::: "memory"); \
                    __builtin_amdgcn_sched_barrier(0); } while (0)

__global__ __launch_bounds__(512, 2) void k_gemm8(
    const unsigned short* __restrict__ A,
    const unsigned short* __restrict__ Bt,
    unsigned short* __restrict__ C,
    const float* __restrict__ mu, const float* __restrict__ rstd,
    const float* __restrict__ c1, const float* __restrict__ c2)
{
  constexpr int NKT = 16;                     // K=1024 / BK=64
  __shared__ __attribute__((aligned(16))) char lds[131072];

  int bid = blockIdx.x;
  { const int nwg = gridDim.x; const int q = nwg >> 3; bid = (bid & 7) * q + (bid >> 3); }
  const int mt = bid >> 2, nt = bid & 3;      // ntiles=4, nt fastest: share A panel
  const int tid = threadIdx.x;
  const int wid = tid >> 6, lane = tid & 63;
  const int g = lane >> 4, c = lane & 15;
  const int wr = wid >> 2, wc = wid & 3;
  const int MO = wr * 128, NO = wc * 64;

  const unsigned short* gA = A + (size_t)mt * 256 * 1024;
  const unsigned short* gB = Bt + (size_t)nt * 256 * 1024;

  const f32x4 zz = {0.f, 0.f, 0.f, 0.f};
  f32x4 acc[8][4];
  #pragma unroll
  for (int m = 0; m < 8; ++m)
    #pragma unroll
    for (int n = 0; n < 4; ++n) acc[m][n] = zz;

  // ---- staging: one half-tile (16KB) = 2 x gload16 per thread; linear LDS dest,
  // ---- slot-rotated global source (verified 0-conflict pattern from R3)
  auto stageA = [&](int buf, int kk, int kt) {
    #pragma unroll
    for (int i = 0; i < 2; ++i) {
      const int o = (i * 512 + tid) * 16;
      const int row = o >> 6;
      const int ss = ((((o >> 4) & 3) - (row >> 1)) & 3);
      gload_lds16((const char*)(gA + (size_t)row * 1024 + kt * 64 + kk * 32) + ss * 16,
                  lds + buf * 32768 + kk * 16384 + o);
    }
  };
  auto stageB = [&](int buf, int kk, int kt) {
    #pragma unroll
    for (int i = 0; i < 2; ++i) {
      const int o = (i * 512 + tid) * 16;
      const int row = o >> 6;
      const int ss = ((((o >> 4) & 3) - (row >> 1)) & 3);
      gload_lds16((const char*)(gB + (size_t)row * 1024 + kt * 64 + kk * 32) + ss * 16,
                  lds + 65536 + buf * 32768 + kk * 16384 + o);
    }
  };
  auto rdA = [&](int buf, int kk, int m) -> bfrag8 {
    const int row = MO + m * 16 + c;
    return *(const bfrag8*)(lds + buf * 32768 + kk * 16384 + row * 64
                            + (((g + (row >> 1)) & 3) << 4));
  };
  auto rdB = [&](int buf, int kk, int n) -> bfrag8 {
    const int row = NO + n * 16 + c;
    return *(const bfrag8*)(lds + 65536 + buf * 32768 + kk * 16384 + row * 64
                            + (((g + (row >> 1)) & 3) << 4));
  };

  bfrag8 a[8], b0[4], b1[4];

  // one K-tile = 4 phases; stages tile `ukt` into buffer `sb` (order AK0,BK0,BK1,AK1)
  auto tile4 = [&](int buf, int sb, int ukt) {
    // phase A: reads a(kk0)x8 + b(kk0)x4; MFMA kk0 x n{0,1}
    #pragma unroll
    for (int m = 0; m < 8; ++m) a[m] = rdA(buf, 0, m);
    #pragma unroll
    for (int n = 0; n < 4; ++n) b0[n] = rdB(buf, 0, n);
    stageA(sb, 0, ukt);
    BAR8; LGKM0;
    __builtin_amdgcn_s_setprio(1);
    #pragma unroll
    for (int m = 0; m < 8; ++m) {
      acc[m][0] = __builtin_amdgcn_mfma_f32_16x16x32_bf16(a[m], b0[0], acc[m][0], 0, 0, 0);
      acc[m][1] = __builtin_amdgcn_mfma_f32_16x16x32_bf16(a[m], b0[1], acc[m][1], 0, 0, 0);
    }
    __builtin_amdgcn_s_setprio(0);
    GATE4;
    // phase B: reads b(kk1)x4; MFMA kk0 x n{2,3}
    #pragma unroll
    for (int n = 0; n < 4; ++n) b1[n] = rdB(buf, 1, n);
    stageB(sb, 0, ukt);
    BAR8; LGKM0;
    __builtin_amdgcn_s_setprio(1);
    #pragma unroll
    for (int m = 0; m < 8; ++m) {
      acc[m][2] = __builtin_amdgcn_mfma_f32_16x16x32_bf16(a[m], b0[2], acc[m][2], 0, 0, 0);
      acc[m][3] = __builtin_amdgcn_mfma_f32_16x16x32_bf16(a[m], b0[3], acc[m][3], 0, 0, 0);
    }
    __builtin_amdgcn_s_setprio(0);
    GATE4;
    // phase C: reads a(kk1)x8; MFMA kk1 x n{0,1}
    #pragma unroll
    for (int m = 0; m < 8; ++m) a[m] = rdA(buf, 1, m);
    stageB(sb, 1, ukt);
    BAR8; LGKM0;
    __builtin_amdgcn_s_setprio(1);
    #pragma unroll
    for (int m = 0; m < 8; ++m) {
      acc[m][0] = __builtin_amdgcn_mfma_f32_16x16x32_bf16(a[m], b1[0], acc[m][0], 0, 0, 0);
      acc[m][1] = __builtin_amdgcn_mfma_f32_16x16x32_bf16(a[m], b1[1], acc[m][1], 0, 0, 0);
    }
    __builtin_amdgcn_s_setprio(0);
    BAR8;                                     // no gate: next phase reads nothing new
    // phase D: no reads; MFMA kk1 x n{2,3}
    stageA(sb, 1, ukt);
    BAR8; LGKM0;
    __builtin_amdgcn_s_setprio(1);
    #pragma unroll
    for (int m = 0; m < 8; ++m) {
      acc[m][2] = __builtin_amdgcn_mfma_f32_16x16x32_bf16(a[m], b1[2], acc[m][2], 0, 0, 0);
      acc[m][3] = __builtin_amdgcn_mfma_f32_16x16x32_bf16(a[m], b1[3], acc[m][3], 0, 0, 0);
    }
    __builtin_amdgcn_s_setprio(0);
    GATE4;                                    // gate: next tile's phase A reads
  };

  // prologue: tile 0 -> buf0, same half order as steady state
  stageA(0, 0, 0); stageB(0, 0, 0); stageB(0, 1, 0); stageA(0, 1, 0);
  GATE4;

  for (int t = 0; t < NKT; t += 2) {
    const int u2 = (t + 2 < NKT) ? t + 2 : 0;   // wrap dummy keeps vmcnt uniform
    tile4(0, 1, t + 1);                          // compute t (buf0), stage t+1 -> buf1
    tile4(1, 0, u2);                             // compute t+1 (buf1), stage t+2 -> buf0
  }
  // drain all DMA before epilogue / s_endpgm (dummy wrap stages still in flight)
  asm volatile("s_waitcnt vmcnt(0)" ::: "memory");

  // epilogue: kv = rstd*(acc - mu*c1) + c2 -> bf16
  #pragma unroll
  for (int m = 0; m < 8; ++m) {
    #pragma unroll
    for (int j = 0; j < 4; ++j) {
      const size_t orow = (size_t)mt * 256 + MO + m * 16 + g * 4 + j;
      const float rs = rstd[orow], muv = mu[orow];
      #pragma unroll
      for (int n = 0; n < 4; ++n) {
        const int gcol = nt * 256 + NO + n * 16 + c;
        const float v = rs * (acc[m][n][j] - muv * c1[gcol]) + c2[gcol];
        C[orow * 1024 + gcol] = f2bf(v);
      }
    }
  }
}

// ---------------- pipelined GEMM (q / out): 4 LDS regions, BK=32 ----------------------
// Gate is vmcnt(2*LPS) where LPS = loads/stage: depth-3 prefetch keeps 3 stages (3*LPS
// loads) outstanding at the gate; draining to 2*LPS lands exactly the oldest stage.
// (R4 bug: hardcoded vmcnt(8) with LPS=3 left region-0 loads in flight.)
// MODE 1: plain -> bf16        MODE 2: plain -> f32
template<int BM, int BN, int WM, int WN, int NT, int MODE>
__global__ __launch_bounds__(NT, 2) void k_gemm(
    const unsigned short* __restrict__ A, int lda,
    const unsigned short* __restrict__ Bt, int ldb,
    int K, int mtiles, int ntiles,
    void* __restrict__ Cout, int ldc)
{
  constexpr int BK = 32;
  constexpr int NW = NT / 64;
  constexpr int MF = (BM / WM) / 16;
  constexpr int NF = (BN / WN) / 16;
  constexpr int LA = (BM * BK) / (8 * NT);
  constexpr int LB = (BN * BK) / (8 * NT);
  constexpr int LPS = LA + LB;               // loads per stage
  constexpr int RA = BM * BK;
  constexpr int RB = BN * BK;
  static_assert(WM * WN == NW, "wave grid");
  static_assert(LA >= 1 && LB >= 1, "tile too small for NT");
  static_assert(LPS == 3 || LPS == 4, "gate specialization");

  __shared__ __attribute__((aligned(16))) unsigned short As[4 * RA];
  __shared__ __attribute__((aligned(16))) unsigned short Bs[4 * RB];

  int bid = blockIdx.x;
  {
    const int nwg = gridDim.x;
    if ((nwg & 7) == 0) {
      const int q = nwg >> 3;
      bid = (bid & 7) * q + (bid >> 3);
    }
  }
  const int mt = bid / ntiles, nt = bid % ntiles;
  const int tid = threadIdx.x;
  const int wid = tid >> 6, lane = tid & 63;
  const int g = lane >> 4, c = lane & 15;
  const int wr = wid / WN, wc = wid % WN;
  const int MO = wr * (BM / WM), NO = wc * (BN / WN);
  const int rot = (c >> 1) & 3;

  const unsigned short* gA = A + (size_t)mt * BM * lda;
  const unsigned short* gB = Bt + (size_t)nt * BN * ldb;

  const f32x4 zz = {0.f, 0.f, 0.f, 0.f};
  f32x4 acc[MF][NF];
  #pragma unroll
  for (int m = 0; m < MF; ++m)
    #pragma unroll
    for (int n = 0; n < NF; ++n) acc[m][n] = zz;

  auto stage = [&](int R, int kt) {
    #pragma unroll
    for (int i = 0; i < LA; ++i) {
      const int o = (i * NT + tid) * 16;
      const int row = o >> 6;
      const int slot = (o >> 4) & 3;
      const int srcb = (((slot - ((row >> 1) & 3)) & 3) << 4);
      gload_lds16((const char*)(gA + (size_t)row * lda + kt * BK) + srcb,
                  (char*)(As + R * RA) + o);
    }
    #pragma unroll
    for (int i = 0; i < LB; ++i) {
      const int o = (i * NT + tid) * 16;
      const int row = o >> 6;
      const int slot = (o >> 4) & 3;
      const int srcb = (((slot - ((row >> 1) & 3)) & 3) << 4);
      gload_lds16((const char*)(gB + (size_t)row * ldb + kt * BK) + srcb,
                  (char*)(Bs + R * RB) + o);
    }
  };

  auto compute = [&](int R) {
    const char* as = (const char*)(As + R * RA);
    const char* bs = (const char*)(Bs + R * RB);
    bfrag8 af[MF], bf[NF];
    #pragma unroll
    for (int m = 0; m < MF; ++m) {
      const int rw = MO + m * 16 + c;
      af[m] = *(const bfrag8*)(as + rw * 64 + (((g + rot) & 3) << 4));
    }
    #pragma unroll
    for (int n = 0; n < NF; ++n) {
      const int rw = NO + n * 16 + c;
      bf[n] = *(const bfrag8*)(bs + rw * 64 + (((g + rot) & 3) << 4));
    }
    #pragma unroll
    for (int m = 0; m < MF; ++m)
      #pragma unroll
      for (int n = 0; n < NF; ++n)
        acc[m][n] = __builtin_amdgcn_mfma_f32_16x16x32_bf16(af[m], bf[n], acc[m][n], 0, 0, 0);
  };

  const int nkt = K / BK;
  stage(0, 0); stage(1, 1); stage(2, 2);
  for (int t = 0; t < nkt; t += 4) {
    #pragma unroll
    for (int r = 0; r < 4; ++r) {
      int t3 = t + r + 3; if (t3 >= nkt) t3 -= nkt;
      gate_bar<2 * LPS>();
      __builtin_amdgcn_sched_barrier(0);
      stage((r + 3) & 3, t3);
      compute(r);
    }
  }
  // drain all DMA before epilogue / s_endpgm (wrap dummy stages still in flight)
  asm volatile("s_waitcnt vmcnt(0)" ::: "memory");

  #pragma unroll
  for (int m = 0; m < MF; ++m) {
    #pragma unroll
    for (int j = 0; j < 4; ++j) {
      const size_t orow = (size_t)mt * BM + MO + m * 16 + g * 4 + j;
      #pragma unroll
      for (int n = 0; n < NF; ++n) {
        const int gcol = nt * BN + NO + n * 16 + c;
        const float v = acc[m][n][j];
        if constexpr (MODE == 2) ((float*)Cout)[orow * ldc + gcol] = v;
        else ((unsigned short*)Cout)[orow * ldc + gcol] = f2bf(v);
      }
    }
  }
}

// ---------------- flash attention per (bt, head): 4 waves x 16 queries ----------------
__global__ __launch_bounds__(256) void k_attn(
    const unsigned short* __restrict__ q,   // [BT*64][512] bf16 (scale 1/8 pre-folded)
    const unsigned short* __restrict__ kv,  // [BT*1024][1024] bf16: k | v
    unsigned short* __restrict__ ao)        // [BT*64][512] bf16
{
  __shared__ __attribute__((aligned(16))) unsigned short Vt[64 * 64];  // [d][key] swizzled
  const int bid = blockIdx.x;
  const int bt = bid >> 3, h = bid & 7;
  const int tid = threadIdx.x;
  const int wid = tid >> 6, lane = tid & 63;
  const int g = lane >> 4, c = lane & 15;

  const size_t qoff = ((size_t)bt * 64 + wid * 16 + c) * 512 + h * 64;
  const bfrag8 qf0 = *(const bfrag8*)(q + qoff + g * 8);
  const bfrag8 qf1 = *(const bfrag8*)(q + qoff + 32 + g * 8);

  const f32x4 zz = {0.f, 0.f, 0.f, 0.f};
  f32x4 o[4] = {zz, zz, zz, zz};
  float m_run = -1e30f, l_run = 0.f;

  const size_t kvbase = (size_t)bt * 1024 * 1024;
  const unsigned short* kbase = kv + kvbase + h * 64;
  const unsigned short* vbase = kv + kvbase + 512 + h * 64;

  for (int ch = 0; ch < 16; ++ch) {            // 16 chunks of 64 keys
    #pragma unroll
    for (int rr = 0; rr < 2; ++rr) {           // stage V transposed + XOR-swizzled
      const int key = rr * 32 + (tid >> 3);
      const int d0 = (tid & 7) * 8;
      const bfrag8 vv = *(const bfrag8*)(vbase + (size_t)(ch * 64 + key) * 1024 + d0);
      #pragma unroll
      for (int j = 0; j < 8; ++j)
        Vt[(d0 + j) * 64 + (key ^ (j << 3))] = (unsigned short)vv[j];
    }
    __syncthreads();
    #pragma unroll
    for (int ks = 0; ks < 2; ++ks) {           // 2 x 32-key steps
      const int kb = ch * 64 + ks * 32;
      f32x4 s[2];
      #pragma unroll
      for (int t = 0; t < 2; ++t) {            // key permutation: row m -> key 8*(m>>2)+4t+(m&3)
        const int kr = ((c >> 2) << 3) + (t << 2) + (c & 3);
        const unsigned short* krow = kbase + (size_t)(kb + kr) * 1024;
        s[t] = zz;
        s[t] = __builtin_amdgcn_mfma_f32_16x16x32_bf16(*(const bfrag8*)(krow + g * 8),      qf0, s[t], 0, 0, 0);
        s[t] = __builtin_amdgcn_mfma_f32_16x16x32_bf16(*(const bfrag8*)(krow + 32 + g * 8), qf1, s[t], 0, 0, 0);
      }
      float pm = s[0][0];
      #pragma unroll
      for (int i = 1; i < 4; ++i) pm = fmaxf(pm, s[0][i]);
      #pragma unroll
      for (int i = 0; i < 4; ++i) pm = fmaxf(pm, s[1][i]);
      pm = fmaxf(pm, __shfl_xor(pm, 16));
      pm = fmaxf(pm, __shfl_xor(pm, 32));
      const float mn = fmaxf(m_run, pm);
      const float alpha = __expf(m_run - mn);
      float p[8];
      #pragma unroll
      for (int i = 0; i < 4; ++i) p[i]     = __expf(s[0][i] - mn);
      #pragma unroll
      for (int i = 0; i < 4; ++i) p[4 + i] = __expf(s[1][i] - mn);
      float ts = 0.f;
      #pragma unroll
      for (int i = 0; i < 8; ++i) ts += p[i];
      ts += __shfl_xor(ts, 16);
      ts += __shfl_xor(ts, 32);
      l_run = l_run * alpha + ts;
      m_run = mn;
      float ar[4];
      #pragma unroll
      for (int rj = 0; rj < 4; ++rj) ar[rj] = __shfl(alpha, g * 4 + rj);
      #pragma unroll
      for (int db = 0; db < 4; ++db)
        #pragma unroll
        for (int j = 0; j < 4; ++j) o[db][j] *= ar[j];
      bfrag8 pa;
      #pragma unroll
      for (int i = 0; i < 8; ++i) pa[i] = (short)f2bf(p[i]);
      #pragma unroll
      for (int db = 0; db < 4; ++db) {
        const int d = db * 16 + c;
        const bfrag8 vb = *(const bfrag8*)(Vt + d * 64 + ((ks * 32 + g * 8) ^ ((c & 7) << 3)));
        o[db] = __builtin_amdgcn_mfma_f32_16x16x32_bf16(pa, vb, o[db], 0, 0, 0);
      }
    }
    __syncthreads();
  }
  float lr[4];
  #pragma unroll
  for (int rj = 0; rj < 4; ++rj) lr[rj] = __shfl(l_run, g * 4 + rj);
  #pragma unroll
  for (int db = 0; db < 4; ++db)
    #pragma unroll
    for (int j = 0; j < 4; ++j) {
      const float val = o[db][j] / lr[j];
      ao[((size_t)bt * 64 + wid * 16 + g * 4 + j) * 512 + h * 64 + db * 16 + c] = f2bf(val);
    }
}

// --------------------------------- launch -------------------------------------------
extern "C" void kernel_launch(void* const* d_in, const int* in_sizes, int n_in,
                              void* d_out, int out_size, void* d_ws, size_t ws_size,
                              hipStream_t stream)
{
  const float* x    = (const float*)d_in[0];
  const float* lat  = (const float*)d_in[1];
  const float* nm_w = (const float*)d_in[2];
  const float* nm_b = (const float*)d_in[3];
  const float* nl_w = (const float*)d_in[4];
  const float* nl_b = (const float*)d_in[5];
  const float* Wq   = (const float*)d_in[6];
  const float* Wkv  = (const float*)d_in[7];
  const float* Wout = (const float*)d_in[8];

  char* p = (char*)d_ws;
  auto take = [&](size_t bytes) { char* r = p; p += (bytes + 255) & ~(size_t)255; return r; };
  unsigned short* xb    = (unsigned short*)take(64ull * 1024 * 1024 * 2);  // bf16(x)
  unsigned short* kvb   = (unsigned short*)take(64ull * 1024 * 1024 * 2);  // kv bf16
  unsigned short* lnb   = (unsigned short*)take(4096ull * 2048 * 2);       // LN(latents)
  unsigned short* qbuf  = (unsigned short*)take(4096ull * 512 * 2);        // q (scaled)
  unsigned short* aob   = (unsigned short*)take(4096ull * 512 * 2);        // attn out
  unsigned short* WqT   = (unsigned short*)take(512ull * 2048 * 2);
  unsigned short* WkvT  = (unsigned short*)take(1024ull * 1024 * 2);
  unsigned short* WoutT = (unsigned short*)take(2048ull * 512 * 2);
  float* muv  = (float*)take(65536ull * 4);
  float* rsd  = (float*)take(65536ull * 4);
  float* c1   = (float*)take(1024 * 4);
  float* c2   = (float*)take(1024 * 4);
  float* part = (float*)take(32ull * 1024 * 4);
  if ((size_t)(p - (char*)d_ws) > ws_size) return;  // insufficient workspace: fail loudly

  k_transpose_cast<<<dim3(64 * 16), 256, 0, stream>>>(Wq,   WqT,   2048,  512, nullptr, 0.125f);
  k_transpose_cast<<<dim3(32 * 32), 256, 0, stream>>>(Wkv,  WkvT,  1024, 1024, nm_w,    1.0f);
  k_transpose_cast<<<dim3(16 * 64), 256, 0, stream>>>(Wout, WoutT,  512, 2048, nullptr, 1.0f);
  k_c1c2_part<<<dim3(16, 4), 256, 0, stream>>>(Wkv, nm_w, nm_b, part);
  k_c1c2_red<<<dim3(4), 256, 0, stream>>>(part, c1, c2);
  k_xstats<<<dim3(16384), 256, 0, stream>>>(x, xb, muv, rsd);
  k_lnlat<<<dim3(4096), 256, 0, stream>>>(lat, nl_w, nl_b, lnb);

  // kv = LN(x) @ Wkv (LN in epilogue): [65536 x 1024 x 1024], 8-phase 256^2
  k_gemm8<<<dim3(1024), 512, 0, stream>>>(xb, WkvT, kvb, muv, rsd, c1, c2);
  // q = LN(latents) @ (Wq/8): [4096 x 512 x 2048], 64x128 tiles -> 256 blocks
  k_gemm<64, 128, 1, 4, 256, 1><<<dim3(256), 256, 0, stream>>>(
      lnb, 2048, WqT, 2048, 2048, 64, 4, qbuf, 512);

  k_attn<<<dim3(512), 256, 0, stream>>>(qbuf, kvb, aob);

  // out = attnout @ Wout: [4096 x 2048 x 512] -> f32, 64x128 tiles -> 1024 blocks
  k_gemm<64, 128, 1, 4, 256, 2><<<dim3(1024), 256, 0, stream>>>(
      aob, 512, WoutT, 512, 512, 64, 16, d_out, 2048);
}

// Round 6
// 378.271 us; speedup vs baseline: 1.0280x; 1.0002x over previous
//
#include <hip/hip_runtime.h>

typedef __attribute__((ext_vector_type(8))) short bfrag8;   // 8 x bf16 (4 VGPRs)
typedef __attribute__((ext_vector_type(4))) float f32x4;    // MFMA accumulator

typedef const unsigned int __attribute__((address_space(1)))* gas1_u32;
typedef unsigned int __attribute__((address_space(3)))* gas3_u32;

#define DEV __device__ __forceinline__

DEV unsigned short f2bf(float f) {              // f32 -> bf16 bits, RNE
  unsigned int u = __builtin_bit_cast(unsigned int, f);
  u += 0x7fffu + ((u >> 16) & 1u);
  return (unsigned short)(u >> 16);
}

DEV void gload_lds16(const void* g, void* l) {  // async global->LDS, 16B/lane
  __builtin_amdgcn_global_load_lds((gas1_u32)g, (gas3_u32)l, 16, 0, 0);
}

// counted-wait + barrier; the "memory" clobber doubles as a compiler fence so
// following ds_reads cannot hoist above the gate.
template<int N> DEV void gate_bar();
template<> DEV void gate_bar<4>() { asm volatile("s_waitcnt vmcnt(4)\n\ts_barrier" ::: "memory"); }
template<> DEV void gate_bar<6>() { asm volatile("s_waitcnt vmcnt(6)\n\ts_barrier" ::: "memory"); }
template<> DEV void gate_bar<8>() { asm volatile("s_waitcnt vmcnt(8)\n\ts_barrier" ::: "memory"); }

// ---------------- per-row stats of x + raw bf16 cast (one wave per row) ---------------
__global__ __launch_bounds__(256) void k_xstats(
    const float* __restrict__ x, unsigned short* __restrict__ xb,
    float* __restrict__ mu, float* __restrict__ rstd)
{
  const int wid = threadIdx.x >> 6, lane = threadIdx.x & 63;
  const int row = blockIdx.x * 4 + wid;
  const float* base = x + (size_t)row * 1024;
  float4 v[4];
  #pragma unroll
  for (int i = 0; i < 4; ++i) v[i] = ((const float4*)base)[i * 64 + lane];
  float s = 0.f, q = 0.f;
  #pragma unroll
  for (int i = 0; i < 4; ++i) {
    s += v[i].x + v[i].y + v[i].z + v[i].w;
    q += v[i].x*v[i].x + v[i].y*v[i].y + v[i].z*v[i].z + v[i].w*v[i].w;
  }
  #pragma unroll
  for (int off = 32; off >= 1; off >>= 1) { s += __shfl_xor(s, off); q += __shfl_xor(q, off); }
  const float m  = s * (1.0f/1024.0f);
  const float var = q * (1.0f/1024.0f) - m * m;
  const float rs = rsqrtf(var + 1e-5f);
  if (lane == 0) { mu[row] = m; rstd[row] = rs; }
  unsigned short* ob = xb + (size_t)row * 1024;
  #pragma unroll
  for (int i = 0; i < 4; ++i) {
    ushort4 o;
    o.x = f2bf(v[i].x); o.y = f2bf(v[i].y); o.z = f2bf(v[i].z); o.w = f2bf(v[i].w);
    ((ushort4*)ob)[i * 64 + lane] = o;
  }
}

// ---------------- full LN of latents -> bf16 (block per row of 2048) ---------------
__global__ __launch_bounds__(256) void k_lnlat(
    const float* __restrict__ lat, const float* __restrict__ w,
    const float* __restrict__ b, unsigned short* __restrict__ ln)
{
  const int row = blockIdx.x, tid = threadIdx.x;
  const float* base = lat + (size_t)row * 2048;
  const float4 v0 = ((const float4*)base)[tid];
  const float4 v1 = ((const float4*)base)[256 + tid];
  float s = v0.x+v0.y+v0.z+v0.w + v1.x+v1.y+v1.z+v1.w;
  float q = v0.x*v0.x+v0.y*v0.y+v0.z*v0.z+v0.w*v0.w
          + v1.x*v1.x+v1.y*v1.y+v1.z*v1.z+v1.w*v1.w;
  #pragma unroll
  for (int off = 32; off >= 1; off >>= 1) { s += __shfl_xor(s, off); q += __shfl_xor(q, off); }
  __shared__ float red[8];
  const int wid = tid >> 6, lane = tid & 63;
  if (lane == 0) { red[wid] = s; red[4 + wid] = q; }
  __syncthreads();
  s = red[0] + red[1] + red[2] + red[3];
  q = red[4] + red[5] + red[6] + red[7];
  const float m  = s * (1.0f/2048.0f);
  const float var = q * (1.0f/2048.0f) - m * m;
  const float rs = rsqrtf(var + 1e-5f);
  const float4 w0 = ((const float4*)w)[tid], w1 = ((const float4*)w)[256 + tid];
  const float4 b0 = ((const float4*)b)[tid], b1 = ((const float4*)b)[256 + tid];
  ushort4 o0, o1;
  o0.x = f2bf((v0.x - m) * rs * w0.x + b0.x);
  o0.y = f2bf((v0.y - m) * rs * w0.y + b0.y);
  o0.z = f2bf((v0.z - m) * rs * w0.z + b0.z);
  o0.w = f2bf((v0.w - m) * rs * w0.w + b0.w);
  o1.x = f2bf((v1.x - m) * rs * w1.x + b1.x);
  o1.y = f2bf((v1.y - m) * rs * w1.y + b1.y);
  o1.z = f2bf((v1.z - m) * rs * w1.z + b1.z);
  o1.w = f2bf((v1.w - m) * rs * w1.w + b1.w);
  ((ushort4*)(ln + (size_t)row * 2048))[tid] = o0;
  ((ushort4*)(ln + (size_t)row * 2048))[256 + tid] = o1;
}

// ---------------- tiled transpose + bf16 cast: src[K][N] f32 -> dst[N][K] bf16 --------
__global__ __launch_bounds__(256) void k_transpose_cast(
    const float* __restrict__ src, unsigned short* __restrict__ dst,
    int K, int N, const float* __restrict__ rowscale, float scale)
{
  __shared__ float tile[32][33];
  const int tx = threadIdx.x & 31, ty = threadIdx.x >> 5;
  const int ntiles = N >> 5;
  const int k0 = (blockIdx.x / ntiles) << 5;
  const int n0 = (blockIdx.x % ntiles) << 5;
  #pragma unroll
  for (int r = 0; r < 4; ++r) {
    const int kk = ty + r * 8;
    float v = src[(size_t)(k0 + kk) * N + n0 + tx] * scale;
    if (rowscale) v *= rowscale[k0 + kk];
    tile[kk][tx] = v;
  }
  __syncthreads();
  #pragma unroll
  for (int r = 0; r < 4; ++r) {
    const int nn = ty + r * 8;
    dst[(size_t)(n0 + nn) * K + k0 + tx] = f2bf(tile[tx][nn]);
  }
}

// ---------------- c1/c2 two-stage deterministic reduce -------------------------------
__global__ __launch_bounds__(256) void k_c1c2_part(
    const float* __restrict__ Wkv, const float* __restrict__ w,
    const float* __restrict__ b, float* __restrict__ part)
{
  const int kc = blockIdx.x;                 // 16 chunks of 64 k-rows
  const int n  = blockIdx.y * 256 + threadIdx.x;
  float s1 = 0.f, s2 = 0.f;
  const int k0 = kc * 64;
  for (int k = k0; k < k0 + 64; ++k) {
    const float wv = Wkv[(size_t)k * 1024 + n];
    s1 += w[k] * wv;
    s2 += b[k] * wv;
  }
  part[(size_t)(kc * 2 + 0) * 1024 + n] = s1;
  part[(size_t)(kc * 2 + 1) * 1024 + n] = s2;
}

__global__ __launch_bounds__(256) void k_c1c2_red(
    const float* __restrict__ part, float* __restrict__ c1, float* __restrict__ c2)
{
  const int n = blockIdx.x * 256 + threadIdx.x;
  float s1 = 0.f, s2 = 0.f;
  #pragma unroll
  for (int kc = 0; kc < 16; ++kc) {
    s1 += part[(size_t)(kc * 2 + 0) * 1024 + n];
    s2 += part[(size_t)(kc * 2 + 1) * 1024 + n];
  }
  c1[n] = s1; c2[n] = s2;
}

// =====================================================================================
// kv GEMM, 8-phase, ONE barrier per phase. Tile 256x256, BK=64 (2 kk-halves), 8 waves.
// Phase = {ds_reads, 1 half-tile stage, setprio(1), MFMA, setprio(0), GATE/BAR}.
// No explicit lgkm wait: the compiler emits fine-grained lgkmcnt(N) before each MFMA
// use, so early MFMAs overlap the tail of the LDS reads, and wave skew inside the
// barrier interval overlaps one wave's MFMA with another's reads.
// Hazards: stage(half->buf') vs any read of buf' separated by >=4 barriers; each
// wave's reads are consumed by in-phase MFMAs (so complete before its next barrier);
// GATE's asm memory clobber stops read-hoisting above the vmcnt gate. vmcnt(4) at the
// 3 gates per tile lands exactly the halves the next phase reads (walked: prologue
// order Ak0,Bk0,Bk1,Ak1 == steady-state stage order).
// =====================================================================================
#define BAR8   __builtin_amdgcn_s_barrier()
#define GATE4  gate_bar<4>()

__global__ __launch_bounds__(512, 2) void k_gemm8(
    const unsigned short* __restrict__ A,
    const unsigned short* __restrict__ Bt,
    unsigned short* __restrict__ C,
    const float* __restrict__ mu, const float* __restrict__ rstd,
    const float* __restrict__ c1, const float* __restrict__ c2)
{
  constexpr int NKT = 16;                     // K=1024 / BK=64
  __shared__ __attribute__((aligned(16))) char lds[131072];

  int bid = blockIdx.x;
  { const int nwg = gridDim.x; const int q = nwg >> 3; bid = (bid & 7) * q + (bid >> 3); }
  const int mt = bid >> 2, nt = bid & 3;      // ntiles=4, nt fastest: share A panel
  const int tid = threadIdx.x;
  const int wid = tid >> 6, lane = tid & 63;
  const int g = lane >> 4, c = lane & 15;
  const int wr = wid >> 2, wc = wid & 3;
  const int MO = wr * 128, NO = wc * 64;

  const unsigned short* gA = A + (size_t)mt * 256 * 1024;
  const unsigned short* gB = Bt + (size_t)nt * 256 * 1024;

  const f32x4 zz = {0.f, 0.f, 0.f, 0.f};
  f32x4 acc[8][4];
  #pragma unroll
  for (int m = 0; m < 8; ++m)
    #pragma unroll
    for (int n = 0; n < 4; ++n) acc[m][n] = zz;

  // staging: one half-tile (16KB) = 2 x gload16 per thread; linear LDS dest,
  // slot-rotated global source (verified 0-conflict pattern, R3/R5)
  auto stageA = [&](int buf, int kk, int kt) {
    #pragma unroll
    for (int i = 0; i < 2; ++i) {
      const int o = (i * 512 + tid) * 16;
      const int row = o >> 6;
      const int ss = ((((o >> 4) & 3) - (row >> 1)) & 3);
      gload_lds16((const char*)(gA + (size_t)row * 1024 + kt * 64 + kk * 32) + ss * 16,
                  lds + buf * 32768 + kk * 16384 + o);
    }
  };
  auto stageB = [&](int buf, int kk, int kt) {
    #pragma unroll
    for (int i = 0; i < 2; ++i) {
      const int o = (i * 512 + tid) * 16;
      const int row = o >> 6;
      const int ss = ((((o >> 4) & 3) - (row >> 1)) & 3);
      gload_lds16((const char*)(gB + (size_t)row * 1024 + kt * 64 + kk * 32) + ss * 16,
                  lds + 65536 + buf * 32768 + kk * 16384 + o);
    }
  };
  auto rdA = [&](int buf, int kk, int m) -> bfrag8 {
    const int row = MO + m * 16 + c;
    return *(const bfrag8*)(lds + buf * 32768 + kk * 16384 + row * 64
                            + (((g + (row >> 1)) & 3) << 4));
  };
  auto rdB = [&](int buf, int kk, int n) -> bfrag8 {
    const int row = NO + n * 16 + c;
    return *(const bfrag8*)(lds + 65536 + buf * 32768 + kk * 16384 + row * 64
                            + (((g + (row >> 1)) & 3) << 4));
  };

  bfrag8 a[8], b0[4], b1[4];

  // one K-tile = 4 phases; stages tile `ukt` into buffer `sb` (order AK0,BK0,BK1,AK1)
  auto tile4 = [&](int buf, int sb, int ukt) {
    // phase A: reads a(kk0)x8 + b(kk0)x4; MFMA kk0 x n{0,1}
    #pragma unroll
    for (int m = 0; m < 8; ++m) a[m] = rdA(buf, 0, m);
    #pragma unroll
    for (int n = 0; n < 4; ++n) b0[n] = rdB(buf, 0, n);
    stageA(sb, 0, ukt);
    __builtin_amdgcn_s_setprio(1);
    #pragma unroll
    for (int m = 0; m < 8; ++m) {
      acc[m][0] = __builtin_amdgcn_mfma_f32_16x16x32_bf16(a[m], b0[0], acc[m][0], 0, 0, 0);
      acc[m][1] = __builtin_amdgcn_mfma_f32_16x16x32_bf16(a[m], b0[1], acc[m][1], 0, 0, 0);
    }
    __builtin_amdgcn_s_setprio(0);
    GATE4;
    // phase B: reads b(kk1)x4; MFMA kk0 x n{2,3}
    #pragma unroll
    for (int n = 0; n < 4; ++n) b1[n] = rdB(buf, 1, n);
    stageB(sb, 0, ukt);
    __builtin_amdgcn_s_setprio(1);
    #pragma unroll
    for (int m = 0; m < 8; ++m) {
      acc[m][2] = __builtin_amdgcn_mfma_f32_16x16x32_bf16(a[m], b0[2], acc[m][2], 0, 0, 0);
      acc[m][3] = __builtin_amdgcn_mfma_f32_16x16x32_bf16(a[m], b0[3], acc[m][3], 0, 0, 0);
    }
    __builtin_amdgcn_s_setprio(0);
    GATE4;
    // phase C: reads a(kk1)x8; MFMA kk1 x n{0,1}
    #pragma unroll
    for (int m = 0; m < 8; ++m) a[m] = rdA(buf, 1, m);
    stageB(sb, 1, ukt);
    __builtin_amdgcn_s_setprio(1);
    #pragma unroll
    for (int m = 0; m < 8; ++m) {
      acc[m][0] = __builtin_amdgcn_mfma_f32_16x16x32_bf16(a[m], b1[0], acc[m][0], 0, 0, 0);
      acc[m][1] = __builtin_amdgcn_mfma_f32_16x16x32_bf16(a[m], b1[1], acc[m][1], 0, 0, 0);
    }
    __builtin_amdgcn_s_setprio(0);
    BAR8;                                     // no gate: next phase reads nothing new
    // phase D: no reads; MFMA kk1 x n{2,3}
    stageA(sb, 1, ukt);
    __builtin_amdgcn_s_setprio(1);
    #pragma unroll
    for (int m = 0; m < 8; ++m) {
      acc[m][2] = __builtin_amdgcn_mfma_f32_16x16x32_bf16(a[m], b1[2], acc[m][2], 0, 0, 0);
      acc[m][3] = __builtin_amdgcn_mfma_f32_16x16x32_bf16(a[m], b1[3], acc[m][3], 0, 0, 0);
    }
    __builtin_amdgcn_s_setprio(0);
    GATE4;                                    // gate: next tile's phase A reads
  };

  // prologue: tile 0 -> buf0, same half order as steady state
  stageA(0, 0, 0); stageB(0, 0, 0); stageB(0, 1, 0); stageA(0, 1, 0);
  GATE4;

  for (int t = 0; t < NKT; t += 2) {
    const int u2 = (t + 2 < NKT) ? t + 2 : 0;   // wrap dummy keeps vmcnt uniform
    tile4(0, 1, t + 1);                          // compute t (buf0), stage t+1 -> buf1
    tile4(1, 0, u2);                             // compute t+1 (buf1), stage t+2 -> buf0
  }
  // drain all DMA before epilogue / s_endpgm (dummy wrap stages still in flight)
  asm volatile("s_waitcnt vmcnt(0)" ::: "memory");

  // epilogue: kv = rstd*(acc - mu*c1) + c2 -> bf16
  #pragma unroll
  for (int m = 0; m < 8; ++m) {
    #pragma unroll
    for (int j = 0; j < 4; ++j) {
      const size_t orow = (size_t)mt * 256 + MO + m * 16 + g * 4 + j;
      const float rs = rstd[orow], muv = mu[orow];
      #pragma unroll
      for (int n = 0; n < 4; ++n) {
        const int gcol = nt * 256 + NO + n * 16 + c;
        const float v = rs * (acc[m][n][j] - muv * c1[gcol]) + c2[gcol];
        C[orow * 1024 + gcol] = f2bf(v);
      }
    }
  }
}

// ---------------- pipelined GEMM (q / out): 4 LDS regions, BK=32 ----------------------
// Gate is vmcnt(2*LPS): depth-3 prefetch keeps 3 stages outstanding; draining to 2*LPS
// lands exactly the oldest stage. No sched_barrier: gate asm's memory clobber already
// fences LDS reads; compiler handles read->MFMA lgkm waits fine-grained.
// MODE 1: plain -> bf16        MODE 2: plain -> f32
template<int BM, int BN, int WM, int WN, int NT, int MODE>
__global__ __launch_bounds__(NT, 2) void k_gemm(
    const unsigned short* __restrict__ A, int lda,
    const unsigned short* __restrict__ Bt, int ldb,
    int K, int mtiles, int ntiles,
    void* __restrict__ Cout, int ldc)
{
  constexpr int BK = 32;
  constexpr int NW = NT / 64;
  constexpr int MF = (BM / WM) / 16;
  constexpr int NF = (BN / WN) / 16;
  constexpr int LA = (BM * BK) / (8 * NT);
  constexpr int LB = (BN * BK) / (8 * NT);
  constexpr int LPS = LA + LB;               // loads per stage
  constexpr int RA = BM * BK;
  constexpr int RB = BN * BK;
  static_assert(WM * WN == NW, "wave grid");
  static_assert(LA >= 1 && LB >= 1, "tile too small for NT");
  static_assert(LPS == 3 || LPS == 4, "gate specialization");

  __shared__ __attribute__((aligned(16))) unsigned short As[4 * RA];
  __shared__ __attribute__((aligned(16))) unsigned short Bs[4 * RB];

  int bid = blockIdx.x;
  {
    const int nwg = gridDim.x;
    if ((nwg & 7) == 0) {
      const int q = nwg >> 3;
      bid = (bid & 7) * q + (bid >> 3);
    }
  }
  const int mt = bid / ntiles, nt = bid % ntiles;
  const int tid = threadIdx.x;
  const int wid = tid >> 6, lane = tid & 63;
  const int g = lane >> 4, c = lane & 15;
  const int wr = wid / WN, wc = wid % WN;
  const int MO = wr * (BM / WM), NO = wc * (BN / WN);
  const int rot = (c >> 1) & 3;

  const unsigned short* gA = A + (size_t)mt * BM * lda;
  const unsigned short* gB = Bt + (size_t)nt * BN * ldb;

  const f32x4 zz = {0.f, 0.f, 0.f, 0.f};
  f32x4 acc[MF][NF];
  #pragma unroll
  for (int m = 0; m < MF; ++m)
    #pragma unroll
    for (int n = 0; n < NF; ++n) acc[m][n] = zz;

  auto stage = [&](int R, int kt) {
    #pragma unroll
    for (int i = 0; i < LA; ++i) {
      const int o = (i * NT + tid) * 16;
      const int row = o >> 6;
      const int slot = (o >> 4) & 3;
      const int srcb = (((slot - ((row >> 1) & 3)) & 3) << 4);
      gload_lds16((const char*)(gA + (size_t)row * lda + kt * BK) + srcb,
                  (char*)(As + R * RA) + o);
    }
    #pragma unroll
    for (int i = 0; i < LB; ++i) {
      const int o = (i * NT + tid) * 16;
      const int row = o >> 6;
      const int slot = (o >> 4) & 3;
      const int srcb = (((slot - ((row >> 1) & 3)) & 3) << 4);
      gload_lds16((const char*)(gB + (size_t)row * ldb + kt * BK) + srcb,
                  (char*)(Bs + R * RB) + o);
    }
  };

  auto compute = [&](int R) {
    const char* as = (const char*)(As + R * RA);
    const char* bs = (const char*)(Bs + R * RB);
    bfrag8 af[MF], bf[NF];
    #pragma unroll
    for (int m = 0; m < MF; ++m) {
      const int rw = MO + m * 16 + c;
      af[m] = *(const bfrag8*)(as + rw * 64 + (((g + rot) & 3) << 4));
    }
    #pragma unroll
    for (int n = 0; n < NF; ++n) {
      const int rw = NO + n * 16 + c;
      bf[n] = *(const bfrag8*)(bs + rw * 64 + (((g + rot) & 3) << 4));
    }
    #pragma unroll
    for (int m = 0; m < MF; ++m)
      #pragma unroll
      for (int n = 0; n < NF; ++n)
        acc[m][n] = __builtin_amdgcn_mfma_f32_16x16x32_bf16(af[m], bf[n], acc[m][n], 0, 0, 0);
  };

  const int nkt = K / BK;
  stage(0, 0); stage(1, 1); stage(2, 2);
  for (int t = 0; t < nkt; t += 4) {
    #pragma unroll
    for (int r = 0; r < 4; ++r) {
      int t3 = t + r + 3; if (t3 >= nkt) t3 -= nkt;
      gate_bar<2 * LPS>();
      stage((r + 3) & 3, t3);
      compute(r);
    }
  }
  // drain all DMA before epilogue / s_endpgm (wrap dummy stages still in flight)
  asm volatile("s_waitcnt vmcnt(0)" ::: "memory");

  #pragma unroll
  for (int m = 0; m < MF; ++m) {
    #pragma unroll
    for (int j = 0; j < 4; ++j) {
      const size_t orow = (size_t)mt * BM + MO + m * 16 + g * 4 + j;
      #pragma unroll
      for (int n = 0; n < NF; ++n) {
        const int gcol = nt * BN + NO + n * 16 + c;
        const float v = acc[m][n][j];
        if constexpr (MODE == 2) ((float*)Cout)[orow * ldc + gcol] = v;
        else ((unsigned short*)Cout)[orow * ldc + gcol] = f2bf(v);
      }
    }
  }
}

// ---------------- flash attention per (bt, head): 4 waves x 16 queries ----------------
__global__ __launch_bounds__(256) void k_attn(
    const unsigned short* __restrict__ q,   // [BT*64][512] bf16 (scale 1/8 pre-folded)
    const unsigned short* __restrict__ kv,  // [BT*1024][1024] bf16: k | v
    unsigned short* __restrict__ ao)        // [BT*64][512] bf16
{
  __shared__ __attribute__((aligned(16))) unsigned short Vt[64 * 64];  // [d][key] swizzled
  const int bid = blockIdx.x;
  const int bt = bid >> 3, h = bid & 7;
  const int tid = threadIdx.x;
  const int wid = tid >> 6, lane = tid & 63;
  const int g = lane >> 4, c = lane & 15;

  const size_t qoff = ((size_t)bt * 64 + wid * 16 + c) * 512 + h * 64;
  const bfrag8 qf0 = *(const bfrag8*)(q + qoff + g * 8);
  const bfrag8 qf1 = *(const bfrag8*)(q + qoff + 32 + g * 8);

  const f32x4 zz = {0.f, 0.f, 0.f, 0.f};
  f32x4 o[4] = {zz, zz, zz, zz};
  float m_run = -1e30f, l_run = 0.f;

  const size_t kvbase = (size_t)bt * 1024 * 1024;
  const unsigned short* kbase = kv + kvbase + h * 64;
  const unsigned short* vbase = kv + kvbase + 512 + h * 64;

  for (int ch = 0; ch < 16; ++ch) {            // 16 chunks of 64 keys
    #pragma unroll
    for (int rr = 0; rr < 2; ++rr) {           // stage V transposed + XOR-swizzled
      const int key = rr * 32 + (tid >> 3);
      const int d0 = (tid & 7) * 8;
      const bfrag8 vv = *(const bfrag8*)(vbase + (size_t)(ch * 64 + key) * 1024 + d0);
      #pragma unroll
      for (int j = 0; j < 8; ++j)
        Vt[(d0 + j) * 64 + (key ^ (j << 3))] = (unsigned short)vv[j];
    }
    __syncthreads();
    #pragma unroll
    for (int ks = 0; ks < 2; ++ks) {           // 2 x 32-key steps
      const int kb = ch * 64 + ks * 32;
      f32x4 s[2];
      #pragma unroll
      for (int t = 0; t < 2; ++t) {            // key permutation: row m -> key 8*(m>>2)+4t+(m&3)
        const int kr = ((c >> 2) << 3) + (t << 2) + (c & 3);
        const unsigned short* krow = kbase + (size_t)(kb + kr) * 1024;
        s[t] = zz;
        s[t] = __builtin_amdgcn_mfma_f32_16x16x32_bf16(*(const bfrag8*)(krow + g * 8),      qf0, s[t], 0, 0, 0);
        s[t] = __builtin_amdgcn_mfma_f32_16x16x32_bf16(*(const bfrag8*)(krow + 32 + g * 8), qf1, s[t], 0, 0, 0);
      }
      float pm = s[0][0];
      #pragma unroll
      for (int i = 1; i < 4; ++i) pm = fmaxf(pm, s[0][i]);
      #pragma unroll
      for (int i = 0; i < 4; ++i) pm = fmaxf(pm, s[1][i]);
      pm = fmaxf(pm, __shfl_xor(pm, 16));
      pm = fmaxf(pm, __shfl_xor(pm, 32));
      const float mn = fmaxf(m_run, pm);
      const float alpha = __expf(m_run - mn);
      float p[8];
      #pragma unroll
      for (int i = 0; i < 4; ++i) p[i]     = __expf(s[0][i] - mn);
      #pragma unroll
      for (int i = 0; i < 4; ++i) p[4 + i] = __expf(s[1][i] - mn);
      float ts = 0.f;
      #pragma unroll
      for (int i = 0; i < 8; ++i) ts += p[i];
      ts += __shfl_xor(ts, 16);
      ts += __shfl_xor(ts, 32);
      l_run = l_run * alpha + ts;
      m_run = mn;
      float ar[4];
      #pragma unroll
      for (int rj = 0; rj < 4; ++rj) ar[rj] = __shfl(alpha, g * 4 + rj);
      #pragma unroll
      for (int db = 0; db < 4; ++db)
        #pragma unroll
        for (int j = 0; j < 4; ++j) o[db][j] *= ar[j];
      bfrag8 pa;
      #pragma unroll
      for (int i = 0; i < 8; ++i) pa[i] = (short)f2bf(p[i]);
      #pragma unroll
      for (int db = 0; db < 4; ++db) {
        const int d = db * 16 + c;
        const bfrag8 vb = *(const bfrag8*)(Vt + d * 64 + ((ks * 32 + g * 8) ^ ((c & 7) << 3)));
        o[db] = __builtin_amdgcn_mfma_f32_16x16x32_bf16(pa, vb, o[db], 0, 0, 0);
      }
    }
    __syncthreads();
  }
  float lr[4];
  #pragma unroll
  for (int rj = 0; rj < 4; ++rj) lr[rj] = __shfl(l_run, g * 4 + rj);
  #pragma unroll
  for (int db = 0; db < 4; ++db)
    #pragma unroll
    for (int j = 0; j < 4; ++j) {
      const float val = o[db][j] / lr[j];
      ao[((size_t)bt * 64 + wid * 16 + g * 4 + j) * 512 + h * 64 + db * 16 + c] = f2bf(val);
    }
}

// --------------------------------- launch -------------------------------------------
extern "C" void kernel_launch(void* const* d_in, const int* in_sizes, int n_in,
                              void* d_out, int out_size, void* d_ws, size_t ws_size,
                              hipStream_t stream)
{
  const float* x    = (const float*)d_in[0];
  const float* lat  = (const float*)d_in[1];
  const float* nm_w = (const float*)d_in[2];
  const float* nm_b = (const float*)d_in[3];
  const float* nl_w = (const float*)d_in[4];
  const float* nl_b = (const float*)d_in[5];
  const float* Wq   = (const float*)d_in[6];
  const float* Wkv  = (const float*)d_in[7];
  const float* Wout = (const float*)d_in[8];

  char* p = (char*)d_ws;
  auto take = [&](size_t bytes) { char* r = p; p += (bytes + 255) & ~(size_t)255; return r; };
  unsigned short* xb    = (unsigned short*)take(64ull * 1024 * 1024 * 2);  // bf16(x)
  unsigned short* kvb   = (unsigned short*)take(64ull * 1024 * 1024 * 2);  // kv bf16
  unsigned short* lnb   = (unsigned short*)take(4096ull * 2048 * 2);       // LN(latents)
  unsigned short* qbuf  = (unsigned short*)take(4096ull * 512 * 2);        // q (scaled)
  unsigned short* aob   = (unsigned short*)take(4096ull * 512 * 2);        // attn out
  unsigned short* WqT   = (unsigned short*)take(512ull * 2048 * 2);
  unsigned short* WkvT  = (unsigned short*)take(1024ull * 1024 * 2);
  unsigned short* WoutT = (unsigned short*)take(2048ull * 512 * 2);
  float* muv  = (float*)take(65536ull * 4);
  float* rsd  = (float*)take(65536ull * 4);
  float* c1   = (float*)take(1024 * 4);
  float* c2   = (float*)take(1024 * 4);
  float* part = (float*)take(32ull * 1024 * 4);
  if ((size_t)(p - (char*)d_ws) > ws_size) return;  // insufficient workspace: fail loudly

  k_transpose_cast<<<dim3(64 * 16), 256, 0, stream>>>(Wq,   WqT,   2048,  512, nullptr, 0.125f);
  k_transpose_cast<<<dim3(32 * 32), 256, 0, stream>>>(Wkv,  WkvT,  1024, 1024, nm_w,    1.0f);
  k_transpose_cast<<<dim3(16 * 64), 256, 0, stream>>>(Wout, WoutT,  512, 2048, nullptr, 1.0f);
  k_c1c2_part<<<dim3(16, 4), 256, 0, stream>>>(Wkv, nm_w, nm_b, part);
  k_c1c2_red<<<dim3(4), 256, 0, stream>>>(part, c1, c2);
  k_xstats<<<dim3(16384), 256, 0, stream>>>(x, xb, muv, rsd);
  k_lnlat<<<dim3(4096), 256, 0, stream>>>(lat, nl_w, nl_b, lnb);

  // kv = LN(x) @ Wkv (LN in epilogue): [65536 x 1024 x 1024], 8-phase 256^2
  k_gemm8<<<dim3(1024), 512, 0, stream>>>(xb, WkvT, kvb, muv, rsd, c1, c2);
  // q = LN(latents) @ (Wq/8): [4096 x 512 x 2048], 64x128 tiles -> 256 blocks
  k_gemm<64, 128, 1, 4, 256, 1><<<dim3(256), 256, 0, stream>>>(
      lnb, 2048, WqT, 2048, 2048, 64, 4, qbuf, 512);

  k_attn<<<dim3(512), 256, 0, stream>>>(qbuf, kvb, aob);

  // out = attnout @ Wout: [4096 x 2048 x 512] -> f32, 64x128 tiles -> 1024 blocks
  k_gemm<64, 128, 1, 4, 256, 2><<<dim3(1024), 256, 0, stream>>>(
      aob, 512, WoutT, 512, 512, 64, 16, d_out, 2048);
}